// Round 1
// baseline (1421.707 us; speedup 1.0000x reference)
//
#include <hip/hip_runtime.h>
#include <hip/hip_bf16.h>

// GraphSAGE forward: proj -> sage1 -> sage2 -> cls
// N=200000 nodes, E=3200000 edges, IN_DIM=165, HID=64
//
// Strategy: build CSR (dst -> list of src) on device each call (histogram +
// scan + scatter, int atomics only), then pull-mode aggregation fused with
// the 64x64 matmuls: one wave per node, lane = feature, shuffle-broadcast
// matmul. All fp32.

#define NNODES 200000
#define NEDGES 3200000
#define INDIM 165
#define HID 64

#define SCAN_T 256
#define SCAN_I 8
#define SCAN_CHUNK (SCAN_T * SCAN_I)   // 2048

// ---------------- proj: h0 = relu(x @ Wp + bp), 2 nodes per wave ----------
__global__ void proj_kernel(const float* __restrict__ x,
                            const float* __restrict__ Wp,
                            const float* __restrict__ bp,
                            float* __restrict__ h0, int n) {
  int lane = threadIdx.x & 63;
  int wid  = __builtin_amdgcn_readfirstlane(threadIdx.x >> 6);
  int n0 = (blockIdx.x * 4 + wid) * 2;
  if (n0 >= n) return;
  int n1 = n0 + 1;
  bool has1 = (n1 < n);
  const float* x0 = x + (size_t)n0 * INDIM;
  const float* x1 = x + (size_t)(has1 ? n1 : n0) * INDIM;
  float acc0 = 0.f, acc1 = 0.f;
  #pragma unroll 5
  for (int k = 0; k < INDIM; ++k) {
    float w = Wp[k * HID + lane];
    acc0 += x0[k] * w;
    acc1 += x1[k] * w;
  }
  float b = bp[lane];
  acc0 = fmaxf(acc0 + b, 0.f);
  acc1 = fmaxf(acc1 + b, 0.f);
  h0[(size_t)n0 * HID + lane] = acc0;
  if (has1) h0[(size_t)n1 * HID + lane] = acc1;
}

// ---------------- degree histogram ----------------------------------------
__global__ void degree_kernel(const int* __restrict__ dst, int* __restrict__ counts, int e) {
  int i = blockIdx.x * blockDim.x + threadIdx.x;
  if (i < e) atomicAdd(&counts[dst[i]], 1);
}

// ---------------- scan (exclusive prefix over counts -> row_ptr) ----------
__global__ void scan1_kernel(const int* __restrict__ counts, int* __restrict__ row_ptr,
                             int* __restrict__ bsums, int n) {
  __shared__ int lds[SCAN_T];
  int b = blockIdx.x, t = threadIdx.x;
  int base = b * SCAN_CHUNK + t * SCAN_I;
  int v[SCAN_I];
  int s = 0;
  #pragma unroll
  for (int i = 0; i < SCAN_I; ++i) {
    int idx = base + i;
    v[i] = (idx < n) ? counts[idx] : 0;
    s += v[i];
  }
  lds[t] = s;
  __syncthreads();
  for (int off = 1; off < SCAN_T; off <<= 1) {
    int y = (t >= off) ? lds[t - off] : 0;
    __syncthreads();
    lds[t] += y;
    __syncthreads();
  }
  int incl = lds[t];
  int run = incl - s;  // exclusive prefix for this thread's chunk
  #pragma unroll
  for (int i = 0; i < SCAN_I; ++i) {
    int idx = base + i;
    if (idx < n) row_ptr[idx] = run;
    run += v[i];
  }
  if (t == SCAN_T - 1) bsums[b] = incl;
}

__global__ void scan2_kernel(int* __restrict__ bsums, int nb) {
  __shared__ int lds[SCAN_T];
  int t = threadIdx.x;
  int v = (t < nb) ? bsums[t] : 0;
  lds[t] = v;
  __syncthreads();
  for (int off = 1; off < SCAN_T; off <<= 1) {
    int y = (t >= off) ? lds[t - off] : 0;
    __syncthreads();
    lds[t] += y;
    __syncthreads();
  }
  if (t < nb) bsums[t] = lds[t] - v;  // exclusive
}

__global__ void scan3_kernel(int* __restrict__ row_ptr, const int* __restrict__ bsums,
                             int* __restrict__ cursor, int n, int e) {
  int i = blockIdx.x * blockDim.x + threadIdx.x;
  if (i < n) {
    int v = row_ptr[i] + bsums[i / SCAN_CHUNK];
    row_ptr[i] = v;
    cursor[i] = v;
  }
  if (i == n) row_ptr[n] = e;
}

// ---------------- scatter edges into CSR buckets --------------------------
__global__ void scatter_kernel(const int* __restrict__ src, const int* __restrict__ dst,
                               int* __restrict__ cursor, int* __restrict__ csr_src, int e) {
  int i = blockIdx.x * blockDim.x + threadIdx.x;
  if (i < e) {
    int d = dst[i];
    int pos = atomicAdd(&cursor[d], 1);
    csr_src[pos] = src[i];
  }
}

// ---------------- fused SAGE layer: pull-aggregate + matmul ---------------
// hout[node] = relu( mean_aggr(hin)[node] @ Wl + bl + hin[node] @ Wr )
__global__ void sage_kernel(const float* __restrict__ hin,
                            const int* __restrict__ row_ptr,
                            const int* __restrict__ csr_src,
                            const float* __restrict__ Wl, const float* __restrict__ bl,
                            const float* __restrict__ Wr,
                            float* __restrict__ hout, int n) {
  int lane = threadIdx.x & 63;
  int wid  = __builtin_amdgcn_readfirstlane(threadIdx.x >> 6);
  int node = blockIdx.x * 4 + wid;
  if (node >= n) return;
  int r0 = row_ptr[node];
  int r1 = row_ptr[node + 1];
  float acc = 0.f;
  for (int p = r0; p < r1; ++p) {
    int s = csr_src[p];
    acc += hin[(size_t)s * HID + lane];
  }
  int deg = r1 - r0;
  float rdeg = 1.0f / (float)(deg > 1 ? deg : 1);
  acc *= rdeg;
  float self = hin[(size_t)node * HID + lane];

  float out = bl[lane];
  #pragma unroll
  for (int k = 0; k < HID; ++k) {
    float a  = __shfl(acc, k, 64);
    float s2 = __shfl(self, k, 64);
    out += a * Wl[k * HID + lane] + s2 * Wr[k * HID + lane];
  }
  hout[(size_t)node * HID + lane] = fmaxf(out, 0.f);
}

// ---------------- classifier: out = h @ Wc + bc ---------------------------
__global__ void cls_kernel(const float* __restrict__ h, const float* __restrict__ Wc,
                           const float* __restrict__ bc, float* __restrict__ out, int n) {
  int lane = threadIdx.x & 63;
  int wid  = __builtin_amdgcn_readfirstlane(threadIdx.x >> 6);
  int node = blockIdx.x * 4 + wid;
  if (node >= n) return;
  float v = h[(size_t)node * HID + lane] * Wc[lane];
  #pragma unroll
  for (int off = 32; off > 0; off >>= 1) v += __shfl_down(v, off, 64);
  if (lane == 0) out[node] = v + bc[0];
}

extern "C" void kernel_launch(void* const* d_in, const int* in_sizes, int n_in,
                              void* d_out, int out_size, void* d_ws, size_t ws_size,
                              hipStream_t stream) {
  const float* x   = (const float*)d_in[0];
  const int*   ei  = (const int*)d_in[1];
  const float* Wp  = (const float*)d_in[2];
  const float* bp  = (const float*)d_in[3];
  const float* W1l = (const float*)d_in[4];
  const float* b1l = (const float*)d_in[5];
  const float* W1r = (const float*)d_in[6];
  const float* W2l = (const float*)d_in[7];
  const float* b2l = (const float*)d_in[8];
  const float* W2r = (const float*)d_in[9];
  const float* Wc  = (const float*)d_in[10];
  const float* bc  = (const float*)d_in[11];
  float* out = (float*)d_out;

  const int N = NNODES, E = NEDGES;
  const int* src = ei;       // edge_index[0]
  const int* dst = ei + E;   // edge_index[1]

  char* ws = (char*)d_ws;
  // layout (bytes):
  float* h0      = (float*)(ws + 0);                 // 51,200,000
  float* h1      = (float*)(ws + 51200000);          // 51,200,000
  int*   counts  = (int*)  (ws + 102400000);         // 800,000
  int*   row_ptr = (int*)  (ws + 103200000);         // 800,004 (pad to 800,256)
  int*   cursor  = (int*)  (ws + 104000256);         // 800,000
  int*   csr_src = (int*)  (ws + 104800256);         // 12,800,000
  int*   bsums   = (int*)  (ws + 117600256);         // small

  hipMemsetAsync(counts, 0, (size_t)N * 4, stream);

  // proj
  proj_kernel<<<(N + 7) / 8, 256, 0, stream>>>(x, Wp, bp, h0, N);

  // CSR build
  degree_kernel<<<(E + 255) / 256, 256, 0, stream>>>(dst, counts, E);
  int nb = (N + SCAN_CHUNK - 1) / SCAN_CHUNK;  // 98
  scan1_kernel<<<nb, SCAN_T, 0, stream>>>(counts, row_ptr, bsums, N);
  scan2_kernel<<<1, SCAN_T, 0, stream>>>(bsums, nb);
  scan3_kernel<<<(N + 256) / 256, 256, 0, stream>>>(row_ptr, bsums, cursor, N, E);
  scatter_kernel<<<(E + 255) / 256, 256, 0, stream>>>(src, dst, cursor, csr_src, E);

  // two SAGE layers (ping-pong h0 <-> h1)
  sage_kernel<<<(N + 3) / 4, 256, 0, stream>>>(h0, row_ptr, csr_src, W1l, b1l, W1r, h1, N);
  sage_kernel<<<(N + 3) / 4, 256, 0, stream>>>(h1, row_ptr, csr_src, W2l, b2l, W2r, h0, N);

  // classifier
  cls_kernel<<<(N + 3) / 4, 256, 0, stream>>>(h0, Wc, bc, out, N);
}